// Round 3
// baseline (107.927 us; speedup 1.0000x reference)
//
#include <hip/hip_runtime.h>
#include <hip/hip_bf16.h>

#define B_   8
#define N_   16384
#define C_   64
#define M_   256
#define NPB  1048576   // N_*C_ per batch

typedef __attribute__((ext_vector_type(8))) short short8v;   // 8 bf16 = 4 VGPR
typedef __attribute__((ext_vector_type(16))) float f32x16;   // MFMA 32x32 acc

union FragU { short8v s8; unsigned u[4]; };

__device__ inline unsigned pkbf(float a, float b) {
  union { __hip_bfloat162 h2; unsigned u; } cv;
  cv.h2 = __float22bfloat162_rn(make_float2(a, b));
  return cv.u;
}
__device__ inline unsigned short bfbits(float a) {
  union { __hip_bfloat16 h; unsigned short u; } cv;
  cv.h = __float2bfloat16(a);
  return cv.u;
}
__device__ inline short8v ld8(const unsigned short* p) {
  return *(const short8v*)p;
}

// Repack a 32x32 MFMA D-tile (rows r: (reg&3)+8*(reg>>2)+4*hi ; col q=lane&31)
// into two B-operand fragments (frag t: element j holds row 16t+8*hi+j, col q).
__device__ inline void repack16(const f32x16 s, const int hi, FragU& f0, FragU& f1) {
  #pragma unroll
  for (int h = 0; h < 2; ++h) {
    FragU& f = h ? f1 : f0;
    unsigned a0 = pkbf(s[8*h+0], s[8*h+1]);
    unsigned a1 = pkbf(s[8*h+2], s[8*h+3]);
    unsigned a2 = pkbf(s[8*h+4], s[8*h+5]);
    unsigned a3 = pkbf(s[8*h+6], s[8*h+7]);
    unsigned b0 = (unsigned)__shfl_xor((int)a0, 32);
    unsigned b1 = (unsigned)__shfl_xor((int)a1, 32);
    unsigned b2 = (unsigned)__shfl_xor((int)a2, 32);
    unsigned b3 = (unsigned)__shfl_xor((int)a3, 32);
    f.u[0] = hi ? b2 : a0;
    f.u[1] = hi ? b3 : a1;
    f.u[2] = hi ? a2 : b0;
    f.u[3] = hi ? a3 : b1;
  }
}

// ---------------------------------------------------------------------------
// Conv, coalesced: for fixed (par, w, ci) x is contiguous along csrc=oh*4+j,
// so a float4 at csrc=4*oh gives the 4 same-parity kh taps of output row oh.
// Block = (b, ow, kw): K-slice (64 KB) staged in LDS per parity; A-reads are
// wave-broadcast 64B transactions.  grid 1024, fp32 FMA, split-K over kw.
// ---------------------------------------------------------------------------
__global__ __launch_bounds__(256) void conv_gemm(const float* __restrict__ x,
                                                 const float* __restrict__ Kw,
                                                 float* __restrict__ xr_part) {
  __shared__ float Ks[256][64];     // [j*64+ci][co]  = 64 KB
  const int kw  = blockIdx.x & 7;
  const int ow  = (blockIdx.x >> 3) & 15;
  const int b   = blockIdx.x >> 7;
  const int t   = threadIdx.x;
  const int co4 = t & 15;
  const int oh  = t >> 4;

  float acc[4] = {0.f, 0.f, 0.f, 0.f};

  for (int par = 0; par < 2; ++par) {
    __syncthreads();
    for (int i = t; i < 4096; i += 256) {
      const int row = i >> 4;            // j*64+ci
      const int c4  = i & 15;
      const int j = row >> 6, ci = row & 63;
      const int e = ((2 * j + par) * 8 + kw) * 64 + ci;
      *(float4*)&Ks[row][c4 * 4] = *(const float4*)(Kw + (size_t)e * 64 + c4 * 4);
    }
    __syncthreads();
    const float* ax = x + (size_t)b * NPB
                    + ((size_t)par * 8192 + ow * 512 + kw * 64) * 64 + oh * 4;
    #pragma unroll 4
    for (int ci = 0; ci < 64; ++ci) {
      const float4 a4 = *(const float4*)(ax + ci * 64);
      #pragma unroll
      for (int j = 0; j < 4; ++j) {
        const float av = (j == 0) ? a4.x : (j == 1) ? a4.y : (j == 2) ? a4.z : a4.w;
        const float4 k4 = *(const float4*)&Ks[j * 64 + ci][co4 * 4];
        acc[0] += av * k4.x; acc[1] += av * k4.y;
        acc[2] += av * k4.z; acc[3] += av * k4.w;
      }
    }
  }
  float* dst = xr_part + (size_t)kw * (M_ * B_ * 64)
             + ((size_t)(b * M_ + oh * 16 + ow)) * 64 + co4 * 4;
  *(float4*)dst = make_float4(acc[0], acc[1], acc[2], acc[3]);
}

// ---------------------------------------------------------------------------
// Reduce split-K + bias, LayerNorm, kv GEMV (fp32), emit bf16 K and bf16 V^T.
// 4 rows per 256-thread block (one wave per row).
// ---------------------------------------------------------------------------
__global__ __launch_bounds__(256) void ln_kv(const float* __restrict__ xr_part,
                                             const float* __restrict__ sr_bias,
                                             const float* __restrict__ gamma,
                                             const float* __restrict__ beta,
                                             const float* __restrict__ Wkv,
                                             unsigned short* __restrict__ kb16,
                                             unsigned short* __restrict__ vt16) {
  const int w   = threadIdx.x >> 6;
  const int row = blockIdx.x * 4 + w;   // 0..2047  (= b*256 + m)
  const int c   = threadIdx.x & 63;
  float val = sr_bias[c];
  #pragma unroll
  for (int s = 0; s < 8; ++s)
    val += xr_part[(size_t)s * (M_ * B_ * 64) + (size_t)row * 64 + c];

  float sum = val;
  #pragma unroll
  for (int off = 32; off; off >>= 1) sum += __shfl_xor(sum, off, 64);
  const float mu = sum * (1.f / 64.f);
  const float d  = val - mu;
  float vs = d * d;
  #pragma unroll
  for (int off = 32; off; off >>= 1) vs += __shfl_xor(vs, off, 64);
  const float rs = rsqrtf(vs * (1.f / 64.f) + 1e-3f);
  const float ln = d * rs * gamma[c] + beta[c];

  __shared__ float lnrow[4][64];
  lnrow[w][c] = ln;
  __syncthreads();

  float ka = 0.f, va = 0.f;
  #pragma unroll 8
  for (int cc = 0; cc < 64; ++cc) {
    const float l = lnrow[w][cc];
    ka += l * Wkv[cc * 128 + c];
    va += l * Wkv[cc * 128 + 64 + c];
  }
  kb16[(size_t)row * 64 + c] = bfbits(ka);
  const int bb = row >> 8, m = row & 255;
  vt16[(bb << 14) + (c << 8) + m] = bfbits(va);   // V^T [b][d][m]
}

// ---------------------------------------------------------------------------
// Tiny prep: Wq^T and Wp^T in bf16.
// ---------------------------------------------------------------------------
__global__ void prep_w(const float* __restrict__ Wq, const float* __restrict__ Wp,
                       unsigned short* __restrict__ wqt, unsigned short* __restrict__ wpt) {
  const int i = blockIdx.x * 256 + threadIdx.x;
  if (i < 4096) {
    const int co = i >> 6, ci = i & 63;
    wqt[i] = bfbits(Wq[ci * 64 + co]);
    wpt[i] = bfbits(Wp[ci * 64 + co]);
  }
}

// ---------------------------------------------------------------------------
// Fused MFMA attention.  x staged coalesced -> bf16 XOR-swizzled LDS tile;
// Q^T = Wq^T X^T ; S^T = K Q^T ; P=exp(S*scale); O^T = V^T P^T ;
// F^T = Wp^T O^T + bp.  One wave = 32 query rows; 4 waves/block.
// ---------------------------------------------------------------------------
__global__ __launch_bounds__(256) void attn_mfma(const float* __restrict__ x,
                                                 const unsigned short* __restrict__ kb16,
                                                 const unsigned short* __restrict__ vt16,
                                                 const unsigned short* __restrict__ wqt,
                                                 const unsigned short* __restrict__ wpt,
                                                 const float* __restrict__ bp,
                                                 float* __restrict__ out) {
  __shared__ char smraw[128 * 68 * 4];   // union: bf16 x-tile (16KB) / out transpose (34KB)
  const int t    = threadIdx.x;
  const int w    = t >> 6;
  const int lane = t & 63;
  const int l31  = lane & 31;
  const int hi   = lane >> 5;
  const int b    = blockIdx.x >> 7;
  const int tile = blockIdx.x & 127;
  const size_t nrow = (size_t)b * N_ + (size_t)tile * 128;
  const int qrow = w * 32 + l31;

  // ---- stage x tile: coalesced fp32 load -> bf16 swizzled LDS ----
  {
    unsigned* xsu = (unsigned*)smraw;
    const float* xsrc = x + nrow * 64;
    #pragma unroll
    for (int i = 0; i < 8; ++i) {
      const int idx = i * 256 + t;          // 0..2047
      const int row = idx >> 4, c4 = idx & 15;
      const float4 v = *(const float4*)(xsrc + row * 64 + c4 * 4);
      const int u = (row * 64 + ((c4 * 4) ^ ((row & 7) << 3))) >> 1;  // uint idx
      xsu[u]     = pkbf(v.x, v.y);
      xsu[u + 1] = pkbf(v.z, v.w);
    }
  }
  __syncthreads();

  // ---- X^T B-fragments from LDS ----
  FragU xb[4];
  {
    const unsigned short* xs = (const unsigned short*)smraw;
    const int swz = (qrow & 7) << 3;
    #pragma unroll
    for (int tt = 0; tt < 4; ++tt) {
      const int c0 = (16 * tt + 8 * hi) ^ swz;
      xb[tt].s8 = ld8(xs + qrow * 64 + c0);
    }
  }

  // ---- Q^T = Wq^T · X^T  (2 c_out tiles) -> repack to B-frags ----
  FragU Qb[4];
  #pragma unroll
  for (int ct = 0; ct < 2; ++ct) {
    f32x16 qa;
    #pragma unroll
    for (int r = 0; r < 16; ++r) qa[r] = 0.f;
    #pragma unroll
    for (int tt = 0; tt < 4; ++tt) {
      const short8v aw = ld8(wqt + (l31 + 32 * ct) * 64 + 16 * tt + 8 * hi);
      qa = __builtin_amdgcn_mfma_f32_32x32x16_bf16(aw, xb[tt].s8, qa, 0, 0, 0);
    }
    repack16(qa, hi, Qb[2 * ct], Qb[2 * ct + 1]);
  }

  // ---- main attention loop over 8 key tiles of 32 ----
  const unsigned short* kbb = kb16 + b * 16384 + l31 * 64 + 8 * hi;
  const unsigned short* vbb = vt16 + b * 16384 + l31 * 256 + 8 * hi;
  f32x16 O0, O1;
  #pragma unroll
  for (int r = 0; r < 16; ++r) { O0[r] = 0.f; O1[r] = 0.f; }
  float ss = 0.f;

  #pragma unroll 2
  for (int kt = 0; kt < 8; ++kt) {
    f32x16 S;
    #pragma unroll
    for (int r = 0; r < 16; ++r) S[r] = 0.f;
    #pragma unroll
    for (int tt = 0; tt < 4; ++tt) {
      const short8v ak = ld8(kbb + kt * 2048 + 16 * tt);
      S = __builtin_amdgcn_mfma_f32_32x32x16_bf16(ak, Qb[tt].s8, S, 0, 0, 0);
    }
    f32x16 P;
    #pragma unroll
    for (int r = 0; r < 16; ++r) {
      const float pv = __expf(S[r] * 0.125f);   // scale = hd^-0.5 = 1/8
      P[r] = pv; ss += pv;
    }
    FragU f0, f1;
    repack16(P, hi, f0, f1);
    const short8v v00 = ld8(vbb + (2 * kt) * 16);
    const short8v v01 = ld8(vbb + (2 * kt + 1) * 16);
    const short8v v10 = ld8(vbb + 32 * 256 + (2 * kt) * 16);
    const short8v v11 = ld8(vbb + 32 * 256 + (2 * kt + 1) * 16);
    O0 = __builtin_amdgcn_mfma_f32_32x32x16_bf16(v00, f0.s8, O0, 0, 0, 0);
    O0 = __builtin_amdgcn_mfma_f32_32x32x16_bf16(v01, f1.s8, O0, 0, 0, 0);
    O1 = __builtin_amdgcn_mfma_f32_32x32x16_bf16(v10, f0.s8, O1, 0, 0, 0);
    O1 = __builtin_amdgcn_mfma_f32_32x32x16_bf16(v11, f1.s8, O1, 0, 0, 0);
  }

  // ---- normalize, repack O^T, project ----
  ss += __shfl_xor(ss, 32);
  const float inv = 1.f / ss;
  #pragma unroll
  for (int r = 0; r < 16; ++r) { O0[r] *= inv; O1[r] *= inv; }
  FragU Ob[4];
  repack16(O0, hi, Ob[0], Ob[1]);
  repack16(O1, hi, Ob[2], Ob[3]);

  __syncthreads();   // xs-tile no longer needed; reuse smraw as float ot[128][68]
  float* ot = (float*)smraw;

  #pragma unroll
  for (int ct = 0; ct < 2; ++ct) {
    f32x16 F;
    #pragma unroll
    for (int r = 0; r < 16; ++r) F[r] = 0.f;
    #pragma unroll
    for (int tt = 0; tt < 4; ++tt) {
      const short8v aw = ld8(wpt + (l31 + 32 * ct) * 64 + 16 * tt + 8 * hi);
      F = __builtin_amdgcn_mfma_f32_32x32x16_bf16(aw, Ob[tt].s8, F, 0, 0, 0);
    }
    #pragma unroll
    for (int g = 0; g < 4; ++g) {
      const int co = 32 * ct + 8 * g + 4 * hi;
      const float4 bb = *(const float4*)(bp + co);
      *(float4*)&ot[qrow * 68 + co] =
          make_float4(F[4 * g + 0] + bb.x, F[4 * g + 1] + bb.y,
                      F[4 * g + 2] + bb.z, F[4 * g + 3] + bb.w);
    }
  }

  // ---- coalesced store via LDS transpose ----
  __syncthreads();
  float4* out4 = (float4*)(out + nrow * 64);
  #pragma unroll
  for (int i = 0; i < 8; ++i) {
    const int idx = i * 256 + t;
    const int row = idx >> 4, c4 = idx & 15;
    out4[idx] = *(const float4*)&ot[row * 68 + c4 * 4];
  }
}

// ---------------------------------------------------------------------------
extern "C" void kernel_launch(void* const* d_in, const int* in_sizes, int n_in,
                              void* d_out, int out_size, void* d_ws, size_t ws_size,
                              hipStream_t stream) {
  const float* x   = (const float*)d_in[0];
  const float* Wq  = (const float*)d_in[3];
  const float* Wkv = (const float*)d_in[4];
  const float* Kw  = (const float*)d_in[5];
  const float* sb  = (const float*)d_in[6];
  const float* gam = (const float*)d_in[7];
  const float* bet = (const float*)d_in[8];
  const float* Wp  = (const float*)d_in[9];
  const float* bp  = (const float*)d_in[10];
  float* out = (float*)d_out;

  float* xr_part = (float*)d_ws;                                   // 4 MB
  unsigned short* kb16 = (unsigned short*)((char*)d_ws + 4194304); // 256 KB
  unsigned short* vt16 = kb16 + 131072;                            // 256 KB
  unsigned short* wqt  = vt16 + 131072;                            // 8 KB
  unsigned short* wpt  = wqt + 4096;                               // 8 KB

  prep_w<<<16, 256, 0, stream>>>(Wq, Wp, wqt, wpt);
  conv_gemm<<<1024, 256, 0, stream>>>(x, Kw, xr_part);
  ln_kv<<<512, 256, 0, stream>>>(xr_part, sb, gam, bet, Wkv, kb16, vt16);
  attn_mfma<<<1024, 256, 0, stream>>>(x, kb16, vt16, wqt, wpt, bp, out);
}

// Round 4
// 50.773 us; speedup vs baseline: 2.1257x; 2.1257x over previous
//
#include <hip/hip_runtime.h>
#include <hip/hip_bf16.h>

#define B_   8
#define N_   16384
#define C_   64
#define M_   256
#define NPB  1048576   // N_*C_ per batch

typedef __attribute__((ext_vector_type(8))) short short8v;   // 8 bf16 = 4 VGPR
typedef __attribute__((ext_vector_type(16))) float f32x16;   // MFMA 32x32 acc
typedef __attribute__((ext_vector_type(4)))  float f32x4;    // MFMA 16x16 acc

union FragU { short8v s8; unsigned u[4]; };

__device__ inline unsigned pkbf(float a, float b) {
  union { __hip_bfloat162 h2; unsigned u; } cv;
  cv.h2 = __float22bfloat162_rn(make_float2(a, b));
  return cv.u;
}
__device__ inline unsigned short bfbits(float a) {
  union { __hip_bfloat16 h; unsigned short u; } cv;
  cv.h = __float2bfloat16(a);
  return cv.u;
}
__device__ inline float bf2f(unsigned short u) {
  union { unsigned u; float f; } cv;
  cv.u = ((unsigned)u) << 16;
  return cv.f;
}
__device__ inline short8v ld8(const unsigned short* p) {
  return *(const short8v*)p;
}

// v_permlane32_swap_b32: a'={a_lo|b_lo}, b'={a_hi|b_hi}
__device__ inline void plswap(unsigned &a, unsigned &b) {
#if __has_builtin(__builtin_amdgcn_permlane32_swap)
  typedef unsigned uint2v __attribute__((ext_vector_type(2)));
  uint2v r = __builtin_amdgcn_permlane32_swap(a, b, false, false);
  a = r[0]; b = r[1];
#else
  asm volatile("v_permlane32_swap_b32 %0, %1" : "+v"(a), "+v"(b));
#endif
}

// Repack 32x32 MFMA D-tile (row = (reg&3)+8*(reg>>2)+4*hi, col = lane&31) into
// two B-operand fragments (frag t elem j = k-row 16t+8hi+j, col = lane&31).
__device__ inline void repack16(const f32x16 s, FragU& f0, FragU& f1) {
  #pragma unroll
  for (int h = 0; h < 2; ++h) {
    FragU& f = h ? f1 : f0;
    unsigned a0 = pkbf(s[8*h+0], s[8*h+1]);   // rows {0,1}+4hi (+16h)
    unsigned a1 = pkbf(s[8*h+2], s[8*h+3]);   // rows {2,3}+4hi
    unsigned a2 = pkbf(s[8*h+4], s[8*h+5]);   // rows {8,9}+4hi
    unsigned a3 = pkbf(s[8*h+6], s[8*h+7]);   // rows {10,11}+4hi
    plswap(a0, a2);                           // a0 -> rows 8hi+{0,1}; a2 -> 8hi+{4,5}
    plswap(a1, a3);                           // a1 -> rows 8hi+{2,3}; a3 -> 8hi+{6,7}
    f.u[0] = a0; f.u[1] = a1; f.u[2] = a2; f.u[3] = a3;
  }
}

// ---------------------------------------------------------------------------
// Prep: bf16 lane-ordered weight buffers.
//  wql/wpl[((ct*4+tt)*64+l)*8+j] = W[ci= 16tt+8*(l>>5)+j][co= (l&31)+32ct]
//  kbt[(((kw*4+w)*16+s)*64+l)*8+j] = Kw[kh=2*jj+par][kw][ci][co=16w+(l&15)]
//    where e = s*32+8*(l>>4)+j ; par=e>>8, ci=(e>>2)&63, jj=e&3
// ---------------------------------------------------------------------------
__global__ __launch_bounds__(256) void prep(const float* __restrict__ Wq,
                                            const float* __restrict__ Wp,
                                            const float* __restrict__ Kw,
                                            unsigned short* __restrict__ wql,
                                            unsigned short* __restrict__ wpl,
                                            unsigned short* __restrict__ kbt) {
  const int i = blockIdx.x * 256 + threadIdx.x;
  if (i < 8192) {
    const int idx = i & 4095, sel = i >> 12;
    const int j = idx & 7, l = (idx >> 3) & 63, tt = (idx >> 9) & 3, ct = idx >> 11;
    const int ci = 16 * tt + 8 * (l >> 5) + j, co = (l & 31) + 32 * ct;
    const float* W = sel ? Wp : Wq;
    (sel ? wpl : wql)[idx] = bfbits(W[ci * 64 + co]);
  } else if (i < 8192 + 262144) {
    const int idx = i - 8192;
    const int j = idx & 7, l = (idx >> 3) & 63, s = (idx >> 9) & 15;
    const int w = (idx >> 13) & 3, kw = idx >> 15;
    const int e = s * 32 + 8 * (l >> 4) + j;
    const int par = e >> 8, ci = (e >> 2) & 63, jj = e & 3;
    const int kh = 2 * jj + par, co = 16 * w + (l & 15);
    kbt[idx] = bfbits(Kw[(size_t)((kh * 8 + kw) * 64 + ci) * 64 + co]);
  }
}

// ---------------------------------------------------------------------------
// Conv as MFMA GEMM, no LDS.  Block=(b,ow,kw), 4 waves = 4 co-tiles of 16.
// Contraction e=(par*64+ci)*4+j2 (512) as 16 k-steps of 16x16x32.
// A: lane row=oh=l&15, k=8*(l>>4)+j -> two dense float4 x-loads per step.
// B: coalesced ld8 from pre-swizzled kbt.  Split-K over kw -> bf16 partials.
// ---------------------------------------------------------------------------
__global__ __launch_bounds__(256) void conv_mfma(const float* __restrict__ x,
                                                 const unsigned short* __restrict__ kbt,
                                                 unsigned short* __restrict__ xrb) {
  const int kw = blockIdx.x & 7;
  const int ow = (blockIdx.x >> 3) & 15;
  const int b  = blockIdx.x >> 7;
  const int t  = threadIdx.x, w = t >> 6, l = t & 63;
  const int oh = l & 15, kg = l >> 4;

  const float* xb = x + (size_t)b * NPB + (size_t)((ow * 8 + kw) * 64) * 64 + oh * 4;
  const unsigned short* kb = kbt + (size_t)(((kw * 4 + w) * 16) * 64 + l) * 8;

  f32x4 acc = {0.f, 0.f, 0.f, 0.f};
  #pragma unroll
  for (int s = 0; s < 16; ++s) {
    const int eb  = s * 32 + kg * 8;
    const int par = (s >= 8) ? 1 : 0;          // compile-time per iteration
    const int ci  = ((s * 8) + kg * 2) & 63;
    const float* ax = xb + (size_t)par * 524288 + ci * 64;
    const float4 a0 = *(const float4*)(ax);
    const float4 a1 = *(const float4*)(ax + 64);
    (void)eb;
    FragU af;
    af.u[0] = pkbf(a0.x, a0.y); af.u[1] = pkbf(a0.z, a0.w);
    af.u[2] = pkbf(a1.x, a1.y); af.u[3] = pkbf(a1.z, a1.w);
    const short8v bfrag = ld8(kb + s * 512);
    acc = __builtin_amdgcn_mfma_f32_16x16x32_bf16(af.s8, bfrag, acc, 0, 0, 0);
  }
  // D: col = l&15 (co_local), row = (l>>4)*4 + r (oh)
  unsigned short* dst = xrb + (size_t)kw * 131072
                      + ((size_t)b * 256 + ow) * 64 + w * 16 + (l & 15);
  #pragma unroll
  for (int r = 0; r < 4; ++r)
    dst[(size_t)((l >> 4) * 4 + r) * 1024] = bfbits(acc[r]);
}

// ---------------------------------------------------------------------------
// Reduce split-K (bf16 partials) + bias, LayerNorm, kv GEMV; emit K and V
// directly in per-lane MFMA fragment order (kbl / vbl).
// ---------------------------------------------------------------------------
__global__ __launch_bounds__(256) void ln_kv(const unsigned short* __restrict__ xrb,
                                             const float* __restrict__ sr_bias,
                                             const float* __restrict__ gamma,
                                             const float* __restrict__ beta,
                                             const float* __restrict__ Wkv,
                                             unsigned short* __restrict__ kbl,
                                             unsigned short* __restrict__ vbl) {
  const int w   = threadIdx.x >> 6;
  const int row = blockIdx.x * 4 + w;   // 0..2047  (= b*256 + m)
  const int c   = threadIdx.x & 63;
  float val = sr_bias[c];
  #pragma unroll
  for (int s = 0; s < 8; ++s)
    val += bf2f(xrb[(size_t)s * 131072 + (size_t)row * 64 + c]);

  float sum = val;
  #pragma unroll
  for (int off = 32; off; off >>= 1) sum += __shfl_xor(sum, off, 64);
  const float mu = sum * (1.f / 64.f);
  const float d  = val - mu;
  float vs = d * d;
  #pragma unroll
  for (int off = 32; off; off >>= 1) vs += __shfl_xor(vs, off, 64);
  const float rs = rsqrtf(vs * (1.f / 64.f) + 1e-3f);
  const float ln = d * rs * gamma[c] + beta[c];

  __shared__ float lnrow[4][64];
  lnrow[w][c] = ln;
  __syncthreads();

  float ka = 0.f, va = 0.f;
  #pragma unroll 8
  for (int cc = 0; cc < 64; ++cc) {
    const float l = lnrow[w][cc];
    ka += l * Wkv[cc * 128 + c];
    va += l * Wkv[cc * 128 + 64 + c];
  }
  const int m = row & 255, bb = row >> 8;
  // K-frag: value(tt,l,j) = K[kt*32 + (l&31)][16tt + 8*(l>>5) + j]
  kbl[(size_t)bb * 16384
      + (size_t)((((m >> 5) * 4 + (c >> 4)) * 64) + (m & 31) + 32 * ((c >> 3) & 1)) * 8
      + (c & 7)] = bfbits(ka);
  // V-frag: value(ot,kt,f,l,j) = V[kt*32 + f*16 + 8*(l>>5) + j][32*ot + (l&31)]
  vbl[(size_t)bb * 16384
      + (size_t)(((c >> 5) * 8 + (m >> 5)) * 2 + ((m >> 4) & 1)) * 512
      + (size_t)((c & 31) + 32 * ((m >> 3) & 1)) * 8
      + (m & 7)] = bfbits(va);
}

// ---------------------------------------------------------------------------
// Fused MFMA attention; all frag loads coalesced ld8 from lane-ordered bufs.
// Q^T = Wq^T X^T ; S^T = K Q^T ; P = exp(S/8); O^T = V^T P^T ; F^T = Wp^T O^T.
// One wave = 32 query rows; 4 waves/block; 1024 blocks.
// ---------------------------------------------------------------------------
__global__ __launch_bounds__(256, 4) void attn_mfma(const float* __restrict__ x,
                                                    const unsigned short* __restrict__ kbl,
                                                    const unsigned short* __restrict__ vbl,
                                                    const unsigned short* __restrict__ wql,
                                                    const unsigned short* __restrict__ wpl,
                                                    const float* __restrict__ bp,
                                                    float* __restrict__ out) {
  __shared__ float ot[128 * 68];
  const int t    = threadIdx.x;
  const int w    = t >> 6;
  const int l    = t & 63;
  const int l31  = l & 31;
  const int hi   = l >> 5;
  const int b    = blockIdx.x >> 7;
  const int tile = blockIdx.x & 127;
  const size_t nrow = (size_t)b * N_ + (size_t)tile * 128;
  const int qrow = w * 32 + l31;

  // ---- X^T B-fragments: own query row, fp32 -> bf16 ----
  const float* xrow = x + (nrow + qrow) * 64;
  FragU xb[4];
  #pragma unroll
  for (int tt = 0; tt < 4; ++tt) {
    const float* p = xrow + 16 * tt + 8 * hi;
    const float4 x0 = *(const float4*)(p);
    const float4 x1 = *(const float4*)(p + 4);
    xb[tt].u[0] = pkbf(x0.x, x0.y); xb[tt].u[1] = pkbf(x0.z, x0.w);
    xb[tt].u[2] = pkbf(x1.x, x1.y); xb[tt].u[3] = pkbf(x1.z, x1.w);
  }

  // ---- Q^T = Wq^T · X^T -> repack to B-frags ----
  FragU Qb[4];
  #pragma unroll
  for (int ct = 0; ct < 2; ++ct) {
    f32x16 qa;
    #pragma unroll
    for (int r = 0; r < 16; ++r) qa[r] = 0.f;
    #pragma unroll
    for (int tt = 0; tt < 4; ++tt) {
      const short8v aw = ld8(wql + (size_t)((ct * 4 + tt) * 64 + l) * 8);
      qa = __builtin_amdgcn_mfma_f32_32x32x16_bf16(aw, xb[tt].s8, qa, 0, 0, 0);
    }
    repack16(qa, Qb[2 * ct], Qb[2 * ct + 1]);
  }

  // ---- main attention loop over 8 key tiles of 32 ----
  const unsigned short* kfp = kbl + (size_t)b * 16384 + l * 8;
  const unsigned short* vfp = vbl + (size_t)b * 16384 + l * 8;
  f32x16 O0, O1;
  #pragma unroll
  for (int r = 0; r < 16; ++r) { O0[r] = 0.f; O1[r] = 0.f; }
  float ss = 0.f;

  #pragma unroll
  for (int kt = 0; kt < 8; ++kt) {
    // V frags issued early: latency covered by S-MFMA + exp + repack
    const short8v vf00 = ld8(vfp + (size_t)((kt * 2 + 0) * 512));
    const short8v vf01 = ld8(vfp + (size_t)((kt * 2 + 1) * 512));
    const short8v vf10 = ld8(vfp + (size_t)(((8 + kt) * 2 + 0) * 512));
    const short8v vf11 = ld8(vfp + (size_t)(((8 + kt) * 2 + 1) * 512));
    f32x16 S;
    #pragma unroll
    for (int r = 0; r < 16; ++r) S[r] = 0.f;
    #pragma unroll
    for (int tt = 0; tt < 4; ++tt) {
      const short8v ak = ld8(kfp + (size_t)((kt * 4 + tt) * 512));
      S = __builtin_amdgcn_mfma_f32_32x32x16_bf16(ak, Qb[tt].s8, S, 0, 0, 0);
    }
    f32x16 P;
    #pragma unroll
    for (int r = 0; r < 16; ++r) {
      const float pv = __expf(S[r] * 0.125f);   // scale = hd^-0.5 = 1/8
      P[r] = pv; ss += pv;
    }
    FragU f0, f1;
    repack16(P, f0, f1);
    O0 = __builtin_amdgcn_mfma_f32_32x32x16_bf16(vf00, f0.s8, O0, 0, 0, 0);
    O0 = __builtin_amdgcn_mfma_f32_32x32x16_bf16(vf01, f1.s8, O0, 0, 0, 0);
    O1 = __builtin_amdgcn_mfma_f32_32x32x16_bf16(vf10, f0.s8, O1, 0, 0, 0);
    O1 = __builtin_amdgcn_mfma_f32_32x32x16_bf16(vf11, f1.s8, O1, 0, 0, 0);
  }

  // ---- normalize, repack O^T, project ----
  ss += __shfl_xor(ss, 32);
  const float inv = 1.f / ss;
  #pragma unroll
  for (int r = 0; r < 16; ++r) { O0[r] *= inv; O1[r] *= inv; }
  FragU Ob[4];
  repack16(O0, Ob[0], Ob[1]);
  repack16(O1, Ob[2], Ob[3]);

  #pragma unroll
  for (int ct = 0; ct < 2; ++ct) {
    f32x16 F;
    #pragma unroll
    for (int r = 0; r < 16; ++r) F[r] = 0.f;
    #pragma unroll
    for (int tt = 0; tt < 4; ++tt) {
      const short8v aw = ld8(wpl + (size_t)((ct * 4 + tt) * 64 + l) * 8);
      F = __builtin_amdgcn_mfma_f32_32x32x16_bf16(aw, Ob[tt].s8, F, 0, 0, 0);
    }
    #pragma unroll
    for (int g = 0; g < 4; ++g) {
      const int co = 32 * ct + 8 * g + 4 * hi;
      const float4 bb = *(const float4*)(bp + co);
      *(float4*)&ot[qrow * 68 + co] =
          make_float4(F[4 * g + 0] + bb.x, F[4 * g + 1] + bb.y,
                      F[4 * g + 2] + bb.z, F[4 * g + 3] + bb.w);
    }
  }

  // ---- coalesced store via LDS transpose ----
  __syncthreads();
  float4* out4 = (float4*)(out + nrow * 64);
  #pragma unroll
  for (int i = 0; i < 8; ++i) {
    const int idx = i * 256 + t;
    const int row = idx >> 4, c4 = idx & 15;
    out4[idx] = *(const float4*)&ot[row * 68 + c4 * 4];
  }
}

// ---------------------------------------------------------------------------
extern "C" void kernel_launch(void* const* d_in, const int* in_sizes, int n_in,
                              void* d_out, int out_size, void* d_ws, size_t ws_size,
                              hipStream_t stream) {
  const float* x   = (const float*)d_in[0];
  const float* Wq  = (const float*)d_in[3];
  const float* Wkv = (const float*)d_in[4];
  const float* Kw  = (const float*)d_in[5];
  const float* sb  = (const float*)d_in[6];
  const float* gam = (const float*)d_in[7];
  const float* bet = (const float*)d_in[8];
  const float* Wp  = (const float*)d_in[9];
  const float* bp  = (const float*)d_in[10];
  float* out = (float*)d_out;

  unsigned short* xrb = (unsigned short*)d_ws;        // 8*131072 = 2 MB
  unsigned short* kbl = xrb + 1048576;                // 256 KB
  unsigned short* vbl = kbl + 131072;                 // 256 KB
  unsigned short* wql = vbl + 131072;                 // 8 KB
  unsigned short* wpl = wql + 4096;                   // 8 KB
  unsigned short* kbt = wpl + 4096;                   // 512 KB

  prep<<<1057, 256, 0, stream>>>(Wq, Wp, Kw, wql, wpl, kbt);
  conv_mfma<<<1024, 256, 0, stream>>>(x, kbt, xrb);
  ln_kv<<<512, 256, 0, stream>>>(xrb, sb, gam, bet, Wkv, kbl, vbl);
  attn_mfma<<<1024, 256, 0, stream>>>(x, kbl, vbl, wql, wpl, bp, out);
}

// Round 5
// 46.850 us; speedup vs baseline: 2.3036x; 1.0837x over previous
//
#include <hip/hip_runtime.h>
#include <hip/hip_bf16.h>

#define B_   8
#define N_   16384
#define C_   64
#define M_   256
#define NPB  1048576   // N_*C_ per batch

typedef __attribute__((ext_vector_type(8))) short short8v;   // 8 bf16 = 4 VGPR
typedef __attribute__((ext_vector_type(16))) float f32x16;   // MFMA 32x32 acc
typedef __attribute__((ext_vector_type(4)))  float f32x4;    // MFMA 16x16 acc

union FragU { short8v s8; unsigned u[4]; };

__device__ inline unsigned pkbf(float a, float b) {
  union { __hip_bfloat162 h2; unsigned u; } cv;
  cv.h2 = __float22bfloat162_rn(make_float2(a, b));
  return cv.u;
}
__device__ inline unsigned short bfbits(float a) {
  union { __hip_bfloat16 h; unsigned short u; } cv;
  cv.h = __float2bfloat16(a);
  return cv.u;
}
__device__ inline float bf2f(unsigned short u) {
  union { unsigned u; float f; } cv;
  cv.u = ((unsigned)u) << 16;
  return cv.f;
}
__device__ inline short8v ld8(const unsigned short* p) {
  return *(const short8v*)p;
}

// v_permlane32_swap_b32: a'={a_lo|b_lo}, b'={a_hi|b_hi}
__device__ inline void plswap(unsigned &a, unsigned &b) {
#if __has_builtin(__builtin_amdgcn_permlane32_swap)
  typedef unsigned uint2v __attribute__((ext_vector_type(2)));
  uint2v r = __builtin_amdgcn_permlane32_swap(a, b, false, false);
  a = r[0]; b = r[1];
#else
  asm volatile("v_permlane32_swap_b32 %0, %1" : "+v"(a), "+v"(b));
#endif
}

// Repack 32x32 MFMA D-tile (row = (reg&3)+8*(reg>>2)+4*hi, col = lane&31) into
// two B-operand fragments (frag t elem j = k-row 16t+8hi+j, col = lane&31).
__device__ inline void repack16(const f32x16 s, FragU& f0, FragU& f1) {
  #pragma unroll
  for (int h = 0; h < 2; ++h) {
    FragU& f = h ? f1 : f0;
    unsigned a0 = pkbf(s[8*h+0], s[8*h+1]);
    unsigned a1 = pkbf(s[8*h+2], s[8*h+3]);
    unsigned a2 = pkbf(s[8*h+4], s[8*h+5]);
    unsigned a3 = pkbf(s[8*h+6], s[8*h+7]);
    plswap(a0, a2);
    plswap(a1, a3);
    f.u[0] = a0; f.u[1] = a1; f.u[2] = a2; f.u[3] = a3;
  }
}

// ---------------------------------------------------------------------------
// Prep:
//  blocks 0..1023  : kbt — conv B-frags, lane-ordered (as R4)
//  blocks 1024..   : Wk' = (Wk @ Wq^T) * 0.125 ; Wv' = Wv @ Wp   (fp32)
// ---------------------------------------------------------------------------
__global__ __launch_bounds__(256) void prep(const float* __restrict__ Wq,
                                            const float* __restrict__ Wp,
                                            const float* __restrict__ Kw,
                                            const float* __restrict__ Wkv,
                                            unsigned short* __restrict__ kbt,
                                            float* __restrict__ wkp,
                                            float* __restrict__ wvp) {
  const int gi = blockIdx.x;
  if (gi < 1024) {
    const int idx = gi * 256 + threadIdx.x;      // 0..262143
    const int j = idx & 7, l = (idx >> 3) & 63, s = (idx >> 9) & 15;
    const int w = (idx >> 13) & 3, kw = idx >> 15;
    const int e = s * 32 + 8 * (l >> 4) + j;
    const int par = e >> 8, ci = (e >> 2) & 63, jj = e & 3;
    const int kh = 2 * jj + par, co = 16 * w + (l & 15);
    kbt[idx] = bfbits(Kw[(size_t)((kh * 8 + kw) * 64 + ci) * 64 + co]);
  } else {
    const int idx = (gi - 1024) * 256 + threadIdx.x;  // 0..8191
    const int c = idx & 63, cc = (idx >> 6) & 63, sel = idx >> 12;
    float s = 0.f;
    if (sel == 0) {
      #pragma unroll 8
      for (int d = 0; d < 64; ++d) s += Wkv[cc * 128 + d] * Wq[c * 64 + d];
      wkp[cc * 64 + c] = s * 0.125f;
    } else {
      #pragma unroll 8
      for (int d = 0; d < 64; ++d) s += Wkv[cc * 128 + 64 + d] * Wp[d * 64 + c];
      wvp[cc * 64 + c] = s;
    }
  }
}

// ---------------------------------------------------------------------------
// Conv as MFMA GEMM, no LDS (unchanged from R4).
// ---------------------------------------------------------------------------
__global__ __launch_bounds__(256) void conv_mfma(const float* __restrict__ x,
                                                 const unsigned short* __restrict__ kbt,
                                                 unsigned short* __restrict__ xrb) {
  const int kw = blockIdx.x & 7;
  const int ow = (blockIdx.x >> 3) & 15;
  const int b  = blockIdx.x >> 7;
  const int t  = threadIdx.x, w = t >> 6, l = t & 63;
  const int oh = l & 15, kg = l >> 4;

  const float* xb = x + (size_t)b * NPB + (size_t)((ow * 8 + kw) * 64) * 64 + oh * 4;
  const unsigned short* kb = kbt + (size_t)(((kw * 4 + w) * 16) * 64 + l) * 8;

  f32x4 acc = {0.f, 0.f, 0.f, 0.f};
  #pragma unroll
  for (int s = 0; s < 16; ++s) {
    const int par = (s >= 8) ? 1 : 0;
    const int ci  = ((s * 8) + kg * 2) & 63;
    const float* ax = xb + (size_t)par * 524288 + ci * 64;
    const float4 a0 = *(const float4*)(ax);
    const float4 a1 = *(const float4*)(ax + 64);
    FragU af;
    af.u[0] = pkbf(a0.x, a0.y); af.u[1] = pkbf(a0.z, a0.w);
    af.u[2] = pkbf(a1.x, a1.y); af.u[3] = pkbf(a1.z, a1.w);
    const short8v bfrag = ld8(kb + s * 512);
    acc = __builtin_amdgcn_mfma_f32_16x16x32_bf16(af.s8, bfrag, acc, 0, 0, 0);
  }
  unsigned short* dst = xrb + (size_t)kw * 131072
                      + ((size_t)b * 256 + ow) * 64 + w * 16 + (l & 15);
  #pragma unroll
  for (int r = 0; r < 4; ++r)
    dst[(size_t)((l >> 4) * 4 + r) * 1024] = bfbits(acc[r]);
}

// ---------------------------------------------------------------------------
// Reduce split-K + bias, LayerNorm, then the FOLDED weights:
//   K' = LN @ Wk'  (Wk' = Wk Wq^T /8)   V' = LN @ Wv'  (Wv' = Wv Wp)
// emitted directly in per-lane MFMA fragment order (kbl / vbl).
// ---------------------------------------------------------------------------
__global__ __launch_bounds__(256) void ln_kv(const unsigned short* __restrict__ xrb,
                                             const float* __restrict__ sr_bias,
                                             const float* __restrict__ gamma,
                                             const float* __restrict__ beta,
                                             const float* __restrict__ wkp,
                                             const float* __restrict__ wvp,
                                             unsigned short* __restrict__ kbl,
                                             unsigned short* __restrict__ vbl) {
  const int w   = threadIdx.x >> 6;
  const int row = blockIdx.x * 4 + w;   // 0..2047  (= b*256 + m)
  const int c   = threadIdx.x & 63;
  float val = sr_bias[c];
  #pragma unroll
  for (int s = 0; s < 8; ++s)
    val += bf2f(xrb[(size_t)s * 131072 + (size_t)row * 64 + c]);

  float sum = val;
  #pragma unroll
  for (int off = 32; off; off >>= 1) sum += __shfl_xor(sum, off, 64);
  const float mu = sum * (1.f / 64.f);
  const float d  = val - mu;
  float vs = d * d;
  #pragma unroll
  for (int off = 32; off; off >>= 1) vs += __shfl_xor(vs, off, 64);
  const float rs = rsqrtf(vs * (1.f / 64.f) + 1e-3f);
  const float ln = d * rs * gamma[c] + beta[c];

  __shared__ float lnrow[4][64];
  lnrow[w][c] = ln;
  __syncthreads();

  float ka = 0.f, va = 0.f;
  #pragma unroll 8
  for (int cc = 0; cc < 64; ++cc) {
    const float l = lnrow[w][cc];
    ka += l * wkp[cc * 64 + c];
    va += l * wvp[cc * 64 + c];
  }
  const int m = row & 255, bb = row >> 8;
  // K-frag: value(tt,l,j) = K'[kt*32 + (l&31)][16tt + 8*(l>>5) + j]
  kbl[(size_t)bb * 16384
      + (size_t)((((m >> 5) * 4 + (c >> 4)) * 64) + (m & 31) + 32 * ((c >> 3) & 1)) * 8
      + (c & 7)] = bfbits(ka);
  // V-frag: value(ot,kt,f,l,j) = V'[kt*32 + f*16 + 8*(l>>5) + j][32*ot + (l&31)]
  vbl[(size_t)bb * 16384
      + (size_t)(((c >> 5) * 8 + (m >> 5)) * 2 + ((m >> 4) & 1)) * 512
      + (size_t)((c & 31) + 32 * ((m >> 3) & 1)) * 8
      + (m & 7)] = bfbits(va);
}

// ---------------------------------------------------------------------------
// Fused attention, fully folded:  S = K'·X^T ; P = exp(S) ; F^T = V'^T P^T ;
// out = F/ss + bp.  64 MFMA / wave, no Q-GEMM, no proj-GEMM.
// One wave = 32 query rows; 4 waves/block; 1024 blocks.
// ---------------------------------------------------------------------------
__global__ __launch_bounds__(256, 4) void attn_mfma(const float* __restrict__ x,
                                                    const unsigned short* __restrict__ kbl,
                                                    const unsigned short* __restrict__ vbl,
                                                    const float* __restrict__ bp,
                                                    float* __restrict__ out) {
  __shared__ float ot[128 * 68];
  const int t    = threadIdx.x;
  const int w    = t >> 6;
  const int l    = t & 63;
  const int l31  = l & 31;
  const int hi   = l >> 5;
  const int b    = blockIdx.x >> 7;
  const int tile = blockIdx.x & 127;
  const size_t nrow = (size_t)b * N_ + (size_t)tile * 128;
  const int qrow = w * 32 + l31;

  // ---- X^T B-fragments: own query row, fp32 -> bf16 ----
  const float* xrow = x + (nrow + qrow) * 64;
  FragU xb[4];
  #pragma unroll
  for (int tt = 0; tt < 4; ++tt) {
    const float* p = xrow + 16 * tt + 8 * hi;
    const float4 x0 = *(const float4*)(p);
    const float4 x1 = *(const float4*)(p + 4);
    xb[tt].u[0] = pkbf(x0.x, x0.y); xb[tt].u[1] = pkbf(x0.z, x0.w);
    xb[tt].u[2] = pkbf(x1.x, x1.y); xb[tt].u[3] = pkbf(x1.z, x1.w);
  }

  // ---- main attention loop over 8 key tiles of 32 ----
  const unsigned short* kfp = kbl + (size_t)b * 16384 + l * 8;
  const unsigned short* vfp = vbl + (size_t)b * 16384 + l * 8;
  f32x16 O0, O1;
  #pragma unroll
  for (int r = 0; r < 16; ++r) { O0[r] = 0.f; O1[r] = 0.f; }
  float ss = 0.f;

  #pragma unroll
  for (int kt = 0; kt < 8; ++kt) {
    // V' frags issued early: latency covered by S-MFMA + exp + repack
    const short8v vf00 = ld8(vfp + (size_t)((kt * 2 + 0) * 512));
    const short8v vf01 = ld8(vfp + (size_t)((kt * 2 + 1) * 512));
    const short8v vf10 = ld8(vfp + (size_t)(((8 + kt) * 2 + 0) * 512));
    const short8v vf11 = ld8(vfp + (size_t)(((8 + kt) * 2 + 1) * 512));
    f32x16 S;
    #pragma unroll
    for (int r = 0; r < 16; ++r) S[r] = 0.f;
    #pragma unroll
    for (int tt = 0; tt < 4; ++tt) {
      const short8v ak = ld8(kfp + (size_t)((kt * 4 + tt) * 512));
      S = __builtin_amdgcn_mfma_f32_32x32x16_bf16(ak, xb[tt].s8, S, 0, 0, 0);
    }
    f32x16 P;
    #pragma unroll
    for (int r = 0; r < 16; ++r) {
      const float pv = __expf(S[r]);   // scale folded into K'
      P[r] = pv; ss += pv;
    }
    FragU f0, f1;
    repack16(P, f0, f1);
    O0 = __builtin_amdgcn_mfma_f32_32x32x16_bf16(vf00, f0.s8, O0, 0, 0, 0);
    O0 = __builtin_amdgcn_mfma_f32_32x32x16_bf16(vf01, f1.s8, O0, 0, 0, 0);
    O1 = __builtin_amdgcn_mfma_f32_32x32x16_bf16(vf10, f0.s8, O1, 0, 0, 0);
    O1 = __builtin_amdgcn_mfma_f32_32x32x16_bf16(vf11, f1.s8, O1, 0, 0, 0);
  }

  // ---- normalize + bias, write D-layout rows (co) to LDS ----
  ss += __shfl_xor(ss, 32);
  const float inv = 1.f / ss;
  #pragma unroll
  for (int g = 0; g < 4; ++g) {
    {
      const int co = 8 * g + 4 * hi;
      const float4 bb = *(const float4*)(bp + co);
      *(float4*)&ot[qrow * 68 + co] =
          make_float4(O0[4 * g + 0] * inv + bb.x, O0[4 * g + 1] * inv + bb.y,
                      O0[4 * g + 2] * inv + bb.z, O0[4 * g + 3] * inv + bb.w);
    }
    {
      const int co = 32 + 8 * g + 4 * hi;
      const float4 bb = *(const float4*)(bp + co);
      *(float4*)&ot[qrow * 68 + co] =
          make_float4(O1[4 * g + 0] * inv + bb.x, O1[4 * g + 1] * inv + bb.y,
                      O1[4 * g + 2] * inv + bb.z, O1[4 * g + 3] * inv + bb.w);
    }
  }

  // ---- coalesced store via LDS transpose ----
  __syncthreads();
  float4* out4 = (float4*)(out + nrow * 64);
  #pragma unroll
  for (int i = 0; i < 8; ++i) {
    const int idx = i * 256 + t;
    const int row = idx >> 4, c4 = idx & 15;
    out4[idx] = *(const float4*)&ot[row * 68 + c4 * 4];
  }
}

// ---------------------------------------------------------------------------
extern "C" void kernel_launch(void* const* d_in, const int* in_sizes, int n_in,
                              void* d_out, int out_size, void* d_ws, size_t ws_size,
                              hipStream_t stream) {
  const float* x   = (const float*)d_in[0];
  const float* Wq  = (const float*)d_in[3];
  const float* Wkv = (const float*)d_in[4];
  const float* Kw  = (const float*)d_in[5];
  const float* sb  = (const float*)d_in[6];
  const float* gam = (const float*)d_in[7];
  const float* bet = (const float*)d_in[8];
  const float* Wp  = (const float*)d_in[9];
  const float* bp  = (const float*)d_in[10];
  float* out = (float*)d_out;

  unsigned short* xrb = (unsigned short*)d_ws;        // 8*131072 = 2 MB
  unsigned short* kbl = xrb + 1048576;                // 256 KB
  unsigned short* vbl = kbl + 131072;                 // 256 KB
  unsigned short* kbt = vbl + 131072;                 // 512 KB
  float* wkp = (float*)(kbt + 262144);                // 16 KB
  float* wvp = wkp + 4096;                            // 16 KB

  prep<<<1056, 256, 0, stream>>>(Wq, Wp, Kw, Wkv, kbt, wkp, wvp);
  conv_mfma<<<1024, 256, 0, stream>>>(x, kbt, xrb);
  ln_kv<<<512, 256, 0, stream>>>(xrb, sb, gam, bet, wkp, wvp, kbl, vbl);
  attn_mfma<<<1024, 256, 0, stream>>>(x, kbl, vbl, bp, out);
}